// Round 11
// baseline (426.523 us; speedup 1.0000x reference)
//
#include <hip/hip_runtime.h>

// 2-layer GRU (B=4096, S=512, IN=4, H=32) + FC(32->32) + FC(32->1), fp32 in/out.
// R10 structure (8 waves = main/helper x layer x hf; lgkm-only barrier; T14
// split x-staging) at HALF batch per block: 8 rows/block, 512 blocks -> 2
// independent blocks per CU. Cross-block latency hiding: while one block's
// waves sit in their recurrence-chain/barrier window, the co-resident block
// issues. MFMA tiles half-empty (free), numerics bit-identical per column.
// Lags (verified R7): M0 step i @ iter i; H1 makes AX1[step i-1] @ iter i;
// M1 step i-2 @ iter i; 514 iterations.

#define SEQ 512
#define LOG2E 1.44269504088896340736f

// lgkm-only barrier: orders LDS producer->consumer without draining vmcnt
#define BSYNC() asm volatile("s_waitcnt lgkmcnt(0)\ns_barrier" ::: "memory")

typedef __attribute__((ext_vector_type(8))) short  short8;
typedef __attribute__((ext_vector_type(4))) float  f32x4;
typedef __attribute__((ext_vector_type(2))) unsigned uint2v;

static __device__ __forceinline__ unsigned short f2bf(float f) {
    unsigned u = __builtin_bit_cast(unsigned, f);
    return (unsigned short)((u + 0x7fffu + ((u >> 16) & 1u)) >> 16);
}
static __device__ __forceinline__ float bf2f(unsigned short b) {
    return __builtin_bit_cast(float, ((unsigned)b) << 16);
}
static __device__ __forceinline__ unsigned cvtpk(float a, float b) {
    unsigned r;
    asm("v_cvt_pk_bf16_f32 %0, %1, %2" : "=v"(r) : "v"(a), "v"(b));
    return r;
}
static __device__ __forceinline__ float sigm(float x) {
    return __builtin_amdgcn_rcpf(1.0f + __builtin_amdgcn_exp2f(-LOG2E * x));
}
static __device__ __forceinline__ float tanh_(float x) {
    return 1.0f - 2.0f * __builtin_amdgcn_rcpf(1.0f + __builtin_amdgcn_exp2f((2.0f * LOG2E) * x));
}

#define MFMA(A, B, C) __builtin_amdgcn_mfma_f32_16x16x32_bf16((A), (B), (C), 0, 0, 0)

// (Whi + Wlo) * B + Cin, chained accumulate (2 MFMAs, depth 2)
static __device__ __forceinline__ f32x4 side2(short8 Wh, short8 Wl, short8 B,
                                              f32x4 Cin) {
    f32x4 a = MFMA(Wh, B, Cin);
    a = MFMA(Wl, B, a);
    return a;
}

static __device__ __forceinline__ void cvt8(const float* p, short8& h8, short8& l8) {
    f32x4 v0 = *(const f32x4*)p;
    f32x4 v1 = *(const f32x4*)(p + 4);
#pragma unroll
    for (int e = 0; e < 8; ++e) {
        float v = (e < 4) ? v0[e] : v1[e - 4];
        unsigned short hb = f2bf(v);
        h8[e] = (short)hb;
        l8[e] = (short)f2bf(v - bf2f(hb));
    }
}

__global__ __launch_bounds__(512, 2) void gru_fused(
    const float* __restrict__ x,
    const float* __restrict__ Wih0, const float* __restrict__ Whh0,
    const float* __restrict__ bih0, const float* __restrict__ bhh0,
    const float* __restrict__ Wih1, const float* __restrict__ Whh1,
    const float* __restrict__ bih1, const float* __restrict__ bhh1,
    const float* __restrict__ Wfc2, const float* __restrict__ bfc2,
    const float* __restrict__ Wfc,  const float* __restrict__ bfc,
    float* __restrict__ out)
{
    const int tid  = threadIdx.x;
    const int lane = tid & 63;
    const int wid  = tid >> 6;          // 0..7  (SIMD = wid & 3)
    const int role = wid >> 2;          // 0 = main, 1 = helper
    const int L    = (wid >> 1) & 1;    // layer
    const int hf   = wid & 1;           // unit half
    const int c    = lane & 15;         // batch col (0..15; only c<8 real)
    const int q    = lane >> 4;         // 0..3
    const int b0   = blockIdx.x * 8;    // 8 real batch rows per block

    // clamp helper for tail rows (cols 8..15 are don't-care lanes)
#define BROW(r) (((b0 + (r)) < 4096) ? (b0 + (r)) : 4095)

    // LDS map (identical to R10):
    //  ST01: h1 frags, 2 bufs x [16][80B] = 2560
    //  ST2 : h2 frags, 2 bufs x [16][80B] = 2560
    //  XS  : x ring, 32 steps x 16 x 16B  = 8192
    //  AX0 : 2 bufs x 6 tiles x 64 x 16B  = 12288
    //  AX1 : same                         = 12288
    //  EP  : epilogue scratch             = 128
    __shared__ __align__(16) char smem[38016];
    char*  ST01 = smem;
    char*  ST2  = smem + 2560;
    f32x4* XS   = (f32x4*)(smem + 5120);
    f32x4* AX0  = (f32x4*)(smem + 13312);
    f32x4* AX1  = (f32x4*)(smem + 25600);
    float* EP   = (float*)(smem + 37888);

    // zero state buffers (h = 0)
    for (int i = tid; i < 1280; i += 512) ((unsigned*)smem)[i] = 0u;

    // stage x steps 0..31
    if (tid < 256) {
        const int row = tid & 15, so = tid >> 4;
#pragma unroll
        for (int k = 0; k < 2; ++k) {
            const int step = so + 16 * k;
            XS[step * 16 + row] =
                *(const f32x4*)(x + ((long)BROW(row) * SEQ + step) * 4);
        }
    }

    const int tts[3] = {hf, 2 + hf, 4 + hf};   // r,z,n tiles for this half

    // ------------- per-role weight setup (wave-uniform branches) -----------
    short8 whhh[3], whhl[3];            // mains: Whh hi/lo
    f32x4  bhv2 = {0, 0, 0, 0};        // mains: bhh n-slice (C-in for j=2)
    f32x4  wx0[12];                     // L0 helper: Wih0 rows fp32
    float  bxs[12];                     // L0 helper: folded biases
    short8 wuh[3], wul[3];              // L1 helper: Wih1 hi/lo
    f32x4  bxv[3];                      // L1 helper: folded biases

    if (role == 0) {
        const float* Whp = L ? Whh1 : Whh0;
        const float* bhp = L ? bhh1 : bhh0;
#pragma unroll
        for (int j = 0; j < 3; ++j)
            cvt8(Whp + (16 * tts[j] + c) * 32 + 8 * q, whhh[j], whhl[j]);
        bhv2 = *(const f32x4*)(bhp + 16 * tts[2] + 4 * q);
    } else if (L == 0) {
#pragma unroll
        for (int j = 0; j < 3; ++j)
#pragma unroll
            for (int r = 0; r < 4; ++r) {
                const int g = 16 * tts[j] + 4 * q + r;
                wx0[4 * j + r] = *(const f32x4*)(Wih0 + g * 4);
                bxs[4 * j + r] = bih0[g] + ((j < 2) ? bhh0[g] : 0.0f);
            }
    } else {
#pragma unroll
        for (int j = 0; j < 3; ++j) {
            cvt8(Wih1 + (16 * tts[j] + c) * 32 + 8 * q, wuh[j], wul[j]);
            f32x4 bb = *(const f32x4*)(bih1 + 16 * tts[j] + 4 * q);
            if (j < 2) bb += *(const f32x4*)(bhh1 + 16 * tts[j] + 4 * q);
            bxv[j] = bb;
        }
    }

    // prologue: L0 helper fills AX0 buf0 with step 0 (direct global x read)
    if (role == 1 && L == 0) {
        f32x4 xv = *(const f32x4*)(x + (long)BROW(c) * (SEQ * 4));
#pragma unroll
        for (int j = 0; j < 3; ++j) {
            f32x4 a;
#pragma unroll
            for (int r = 0; r < 4; ++r) {
                f32x4 w = wx0[4 * j + r];
                a[r] = bxs[4 * j + r] + w[0] * xv[0] + w[1] * xv[1]
                     + w[2] * xv[2] + w[3] * xv[3];
            }
            AX0[tts[j] * 64 + q * 16 + c] = a;
        }
    }

    float hst[4] = {0, 0, 0, 0};   // mains: units 16hf+4q+r, batch c
    f32x4 xr0 = {0, 0, 0, 0}, xr1 = {0, 0, 0, 0};   // T14 staging regs (helpers)
    const int frag_off = c * 80 + q * 16;                 // b128 B-frag read
    const int wr_off   = c * 80 + (16 * hf + 4 * q) * 2;  // b64 D write (hi)

    __syncthreads();

    // ---------------- pipelined main loop: 514 iterations ----------------
#pragma unroll 2
    for (int i = 0; i <= SEQ + 1; ++i) {
        if (role == 0) {
            const bool act = (L == 0) ? (i < SEQ) : (i >= 2);
            if (act) {
                const char*  st;
                const f32x4* axb;
                char*        dst;
                if (L == 0) {
                    st  = ST01 + ((i + 1) & 1) * 1280;
                    axb = AX0 + (i & 1) * 384;
                    dst = ST01 + (i & 1) * 1280;
                } else {
                    st  = ST2 + ((i + 1) & 1) * 1280;
                    axb = AX1 + ((i + 1) & 1) * 384;
                    dst = ST2 + (i & 1) * 1280;
                }
                short8 sfrag = *(const short8*)(st + frag_off);
                f32x4 ax0v = axb[tts[0] * 64 + q * 16 + c];
                f32x4 ax1v = axb[tts[1] * 64 + q * 16 + c];
                f32x4 ax2v = axb[tts[2] * 64 + q * 16 + c];

                f32x4 p0 = side2(whhh[0], whhl[0], sfrag, ax0v);
                f32x4 p1 = side2(whhh[1], whhl[1], sfrag, ax1v);
                f32x4 p2 = side2(whhh[2], whhl[2], sfrag, bhv2);

                float hv[4];
#pragma unroll
                for (int r = 0; r < 4; ++r) {
                    float rg = sigm(p0[r]);
                    float zg = sigm(p1[r]);
                    float ng = tanh_(ax2v[r] + rg * p2[r]);
                    float hN = ng + zg * (hst[r] - ng);
                    hst[r] = hN;
                    hv[r] = hN;
                }
                unsigned w0 = cvtpk(hv[0], hv[1]);
                unsigned w1 = cvtpk(hv[2], hv[3]);
                uint2v wpk = {w0, w1};
                *(uint2v*)(dst + wr_off) = wpk;
            }
        } else if (L == 0) {
            // ---- T14 x staging: issue loads at phase 0, ds_write at phase 8 ----
            if ((i & 15) == 0) {
                const int base = i + 16;
                if (base < SEQ) {
                    const int hidx = tid - 256;          // 0..127
                    const int row = hidx & 15, so = hidx >> 4;
                    xr0 = *(const f32x4*)(x + ((long)BROW(row) * SEQ + base + so) * 4);
                    xr1 = *(const f32x4*)(x + ((long)BROW(row) * SEQ + base + so + 8) * 4);
                }
            } else if ((i & 15) == 8) {
                const int base = i + 8;                  // == issue-time base
                if (base < SEQ) {
                    const int hidx = tid - 256;
                    const int row = hidx & 15, so = hidx >> 4;
                    XS[((base + so) & 31) * 16 + row] = xr0;
                    XS[((base + so + 8) & 31) * 16 + row] = xr1;
                }
            }
            // ---- AX0 for step i+1 (exact fp32 x-matvec) ----
            const int step = i + 1;
            if (step < SEQ) {
                f32x4 xv = XS[(step & 31) * 16 + c];
                f32x4* dstax = AX0 + (step & 1) * 384;
#pragma unroll
                for (int j = 0; j < 3; ++j) {
                    f32x4 a;
#pragma unroll
                    for (int r = 0; r < 4; ++r) {
                        f32x4 w = wx0[4 * j + r];
                        a[r] = bxs[4 * j + r] + w[0] * xv[0] + w[1] * xv[1]
                             + w[2] * xv[2] + w[3] * xv[3];
                    }
                    dstax[tts[j] * 64 + q * 16 + c] = a;
                }
            }
        } else {
            // ---- L1 helper: P[i] = Wih1 * h1[i-1] + biases -> AX1[i&1] ----
            if (i >= 1 && i <= SEQ) {
                const char* us = ST01 + ((i + 1) & 1) * 1280;   // h1[i-1]
                short8 uf = *(const short8*)(us + frag_off);
                f32x4* dstax = AX1 + (i & 1) * 384;
#pragma unroll
                for (int j = 0; j < 3; ++j) {
                    f32x4 a = side2(wuh[j], wul[j], uf, bxv[j]);
                    dstax[tts[j] * 64 + q * 16 + c] = a;
                }
            }
        }
        BSYNC();
    }

    // ---------------- epilogue: out = Weff . h2 + cst ----------------
    if (role == 0 && L == 1) {
        float we[4] = {0, 0, 0, 0};
        const float* w2p = Wfc2 + 16 * hf + 4 * q;
#pragma unroll 8
        for (int j = 0; j < 32; ++j) {
            float wf = Wfc[j];
            f32x4 w2 = *(const f32x4*)(w2p + j * 32);
#pragma unroll
            for (int r = 0; r < 4; ++r) we[r] += wf * w2[r];
        }
        float acc = we[0] * hst[0] + we[1] * hst[1] + we[2] * hst[2] + we[3] * hst[3];
        acc += __shfl_xor(acc, 16);
        acc += __shfl_xor(acc, 32);
        if (q == 0) EP[hf * 16 + c] = acc;
    }
    __syncthreads();
    if (wid == 0 && q == 0 && c < 8) {   // only 8 real batch rows per block
        float cst = bfc[0];
        for (int j = 0; j < 32; ++j) cst += Wfc[j] * bfc2[j];
        out[b0 + c] = EP[c] + EP[16 + c] + cst;
    }
#undef BROW
}

extern "C" void kernel_launch(void* const* d_in, const int* in_sizes, int n_in,
                              void* d_out, int out_size, void* d_ws, size_t ws_size,
                              hipStream_t stream) {
    const float* x    = (const float*)d_in[0];
    const float* Wih0 = (const float*)d_in[1];
    const float* Whh0 = (const float*)d_in[2];
    const float* bih0 = (const float*)d_in[3];
    const float* bhh0 = (const float*)d_in[4];
    const float* Wih1 = (const float*)d_in[5];
    const float* Whh1 = (const float*)d_in[6];
    const float* bih1 = (const float*)d_in[7];
    const float* bhh1 = (const float*)d_in[8];
    const float* Wfc2 = (const float*)d_in[9];
    const float* bfc2 = (const float*)d_in[10];
    const float* Wfc  = (const float*)d_in[11];
    const float* bfc  = (const float*)d_in[12];

    const int nblocks = out_size / 8;  // 4096/8 = 512 -> 2 blocks per CU
    hipLaunchKernelGGL(gru_fused, dim3(nblocks), dim3(512), 0, stream,
                       x, Wih0, Whh0, bih0, bhh0, Wih1, Whh1, bih1, bhh1,
                       Wfc2, bfc2, Wfc, bfc, (float*)d_out);
}

// Round 12
// 231.150 us; speedup vs baseline: 1.8452x; 1.8452x over previous
//
#include <hip/hip_runtime.h>

// 2-layer GRU (B=4096, S=512, IN=4, H=32) + FC(32->32) + FC(32->1), fp32 in/out.
// R10 structure (best, 211us): 8 waves/block = (role: main/helper) x (layer) x
// (unit-half hf); main+helper paired per SIMD; lgkm-only barrier; T14 split
// x-staging. 256 blocks x 16 batch rows.
// R12 changes (chain surgery, structure unchanged):
//  1) mains use PARALLEL hi/lo MFMA (depth-1 + add) instead of chained depth-2
//  2) sigm/tanh use VALU Newton rcp (bit-trick + 2 iters) instead of v_rcp
//     trans op -> 2 trans latencies off the serial gate chain, trans-issue /2
//  3) s_setprio(1) around main compute (paired main/helper per SIMD = T5 regime)
// Lags (verified R7): M0 step i @ iter i; H1 makes AX1[step i-1] @ iter i;
// M1 step i-2 @ iter i; 514 iterations.

#define SEQ 512
#define LOG2E 1.44269504088896340736f

// lgkm-only barrier: orders LDS producer->consumer without draining vmcnt
#define BSYNC() asm volatile("s_waitcnt lgkmcnt(0)\ns_barrier" ::: "memory")

typedef __attribute__((ext_vector_type(8))) short  short8;
typedef __attribute__((ext_vector_type(4))) float  f32x4;
typedef __attribute__((ext_vector_type(2))) unsigned uint2v;

static __device__ __forceinline__ unsigned short f2bf(float f) {
    unsigned u = __builtin_bit_cast(unsigned, f);
    return (unsigned short)((u + 0x7fffu + ((u >> 16) & 1u)) >> 16);
}
static __device__ __forceinline__ float bf2f(unsigned short b) {
    return __builtin_bit_cast(float, ((unsigned)b) << 16);
}
static __device__ __forceinline__ unsigned cvtpk(float a, float b) {
    unsigned r;
    asm("v_cvt_pk_bf16_f32 %0, %1, %2" : "=v"(r) : "v"(a), "v"(b));
    return r;
}
// VALU reciprocal: bit-trick estimate + 2 Newton iterations (~6e-6 rel).
// Keeps the reciprocal off the trans pipe and its ~35cy latency off the chain.
static __device__ __forceinline__ float vrcp(float d) {
    unsigned u = 0x7EF311C3u - __builtin_bit_cast(unsigned, d);
    float y = __builtin_bit_cast(float, u);
    y = y * (2.0f - d * y);
    y = y * (2.0f - d * y);
    return y;
}
static __device__ __forceinline__ float sigm(float x) {
    return vrcp(1.0f + __builtin_amdgcn_exp2f(-LOG2E * x));
}
static __device__ __forceinline__ float tanh_(float x) {
    return 1.0f - 2.0f * vrcp(1.0f + __builtin_amdgcn_exp2f((2.0f * LOG2E) * x));
}

#define MFMA(A, B, C) __builtin_amdgcn_mfma_f32_16x16x32_bf16((A), (B), (C), 0, 0, 0)

// chained (helpers, off-chain): (Whi + Wlo) * B + Cin, depth 2
static __device__ __forceinline__ f32x4 side2(short8 Wh, short8 Wl, short8 B,
                                              f32x4 Cin) {
    f32x4 a = MFMA(Wh, B, Cin);
    a = MFMA(Wl, B, a);
    return a;
}
// parallel (mains, on-chain): depth 1 + VALU add
static __device__ __forceinline__ f32x4 side2p(short8 Wh, short8 Wl, short8 B,
                                               f32x4 Cin) {
    f32x4 zero = {0.0f, 0.0f, 0.0f, 0.0f};
    f32x4 p = MFMA(Wh, B, Cin);
    f32x4 s = MFMA(Wl, B, zero);
    return p + s;
}

static __device__ __forceinline__ void cvt8(const float* p, short8& h8, short8& l8) {
    f32x4 v0 = *(const f32x4*)p;
    f32x4 v1 = *(const f32x4*)(p + 4);
#pragma unroll
    for (int e = 0; e < 8; ++e) {
        float v = (e < 4) ? v0[e] : v1[e - 4];
        unsigned short hb = f2bf(v);
        h8[e] = (short)hb;
        l8[e] = (short)f2bf(v - bf2f(hb));
    }
}

__global__ __launch_bounds__(512, 1) void gru_fused(
    const float* __restrict__ x,
    const float* __restrict__ Wih0, const float* __restrict__ Whh0,
    const float* __restrict__ bih0, const float* __restrict__ bhh0,
    const float* __restrict__ Wih1, const float* __restrict__ Whh1,
    const float* __restrict__ bih1, const float* __restrict__ bhh1,
    const float* __restrict__ Wfc2, const float* __restrict__ bfc2,
    const float* __restrict__ Wfc,  const float* __restrict__ bfc,
    float* __restrict__ out)
{
    const int tid  = threadIdx.x;
    const int lane = tid & 63;
    const int wid  = tid >> 6;          // 0..7  (SIMD = wid & 3)
    const int role = wid >> 2;          // 0 = main, 1 = helper
    const int L    = (wid >> 1) & 1;    // layer
    const int hf   = wid & 1;           // unit half
    const int c    = lane & 15;         // batch col
    const int q    = lane >> 4;         // 0..3
    const int b0   = blockIdx.x * 16;

    // LDS map:
    //  ST01: h1 frags, 2 bufs x [16][80B] = 2560
    //  ST2 : h2 frags, 2 bufs x [16][80B] = 2560
    //  XS  : x ring, 32 steps x 16 x 16B  = 8192
    //  AX0 : 2 bufs x 6 tiles x 64 x 16B  = 12288
    //  AX1 : same                         = 12288
    //  EP  : epilogue scratch             = 128
    __shared__ __align__(16) char smem[38016];
    char*  ST01 = smem;
    char*  ST2  = smem + 2560;
    f32x4* XS   = (f32x4*)(smem + 5120);
    f32x4* AX0  = (f32x4*)(smem + 13312);
    f32x4* AX1  = (f32x4*)(smem + 25600);
    float* EP   = (float*)(smem + 37888);

    // zero state buffers (h = 0)
    for (int i = tid; i < 1280; i += 512) ((unsigned*)smem)[i] = 0u;

    // stage x steps 0..31
    if (tid < 256) {
        const int row = tid & 15, so = tid >> 4;
#pragma unroll
        for (int k = 0; k < 2; ++k) {
            const int step = so + 16 * k;
            XS[step * 16 + row] =
                *(const f32x4*)(x + ((long)(b0 + row) * SEQ + step) * 4);
        }
    }

    const int tts[3] = {hf, 2 + hf, 4 + hf};   // r,z,n tiles for this half

    // ------------- per-role weight setup (wave-uniform branches) -----------
    short8 whhh[3], whhl[3];            // mains: Whh hi/lo
    f32x4  bhv2 = {0, 0, 0, 0};        // mains: bhh n-slice (C-in for j=2)
    f32x4  wx0[12];                     // L0 helper: Wih0 rows fp32
    float  bxs[12];                     // L0 helper: folded biases
    short8 wuh[3], wul[3];              // L1 helper: Wih1 hi/lo
    f32x4  bxv[3];                      // L1 helper: folded biases

    if (role == 0) {
        const float* Whp = L ? Whh1 : Whh0;
        const float* bhp = L ? bhh1 : bhh0;
#pragma unroll
        for (int j = 0; j < 3; ++j)
            cvt8(Whp + (16 * tts[j] + c) * 32 + 8 * q, whhh[j], whhl[j]);
        bhv2 = *(const f32x4*)(bhp + 16 * tts[2] + 4 * q);
    } else if (L == 0) {
#pragma unroll
        for (int j = 0; j < 3; ++j)
#pragma unroll
            for (int r = 0; r < 4; ++r) {
                const int g = 16 * tts[j] + 4 * q + r;
                wx0[4 * j + r] = *(const f32x4*)(Wih0 + g * 4);
                bxs[4 * j + r] = bih0[g] + ((j < 2) ? bhh0[g] : 0.0f);
            }
    } else {
#pragma unroll
        for (int j = 0; j < 3; ++j) {
            cvt8(Wih1 + (16 * tts[j] + c) * 32 + 8 * q, wuh[j], wul[j]);
            f32x4 bb = *(const f32x4*)(bih1 + 16 * tts[j] + 4 * q);
            if (j < 2) bb += *(const f32x4*)(bhh1 + 16 * tts[j] + 4 * q);
            bxv[j] = bb;
        }
    }

    // prologue: L0 helper fills AX0 buf0 with step 0 (direct global x read)
    if (role == 1 && L == 0) {
        f32x4 xv = *(const f32x4*)(x + (long)(b0 + c) * (SEQ * 4));
#pragma unroll
        for (int j = 0; j < 3; ++j) {
            f32x4 a;
#pragma unroll
            for (int r = 0; r < 4; ++r) {
                f32x4 w = wx0[4 * j + r];
                a[r] = bxs[4 * j + r] + w[0] * xv[0] + w[1] * xv[1]
                     + w[2] * xv[2] + w[3] * xv[3];
            }
            AX0[tts[j] * 64 + q * 16 + c] = a;
        }
    }

    float hst[4] = {0, 0, 0, 0};   // mains: units 16hf+4q+r, batch c
    f32x4 xr0 = {0, 0, 0, 0}, xr1 = {0, 0, 0, 0};   // T14 staging regs (helpers)
    const int frag_off = c * 80 + q * 16;                 // b128 B-frag read
    const int wr_off   = c * 80 + (16 * hf + 4 * q) * 2;  // b64 D write (hi)

    __syncthreads();

    // ---------------- pipelined main loop: 514 iterations ----------------
#pragma unroll 2
    for (int i = 0; i <= SEQ + 1; ++i) {
        if (role == 0) {
            const bool act = (L == 0) ? (i < SEQ) : (i >= 2);
            if (act) {
                __builtin_amdgcn_s_setprio(1);
                const char*  st;
                const f32x4* axb;
                char*        dst;
                if (L == 0) {
                    st  = ST01 + ((i + 1) & 1) * 1280;
                    axb = AX0 + (i & 1) * 384;
                    dst = ST01 + (i & 1) * 1280;
                } else {
                    st  = ST2 + ((i + 1) & 1) * 1280;
                    axb = AX1 + ((i + 1) & 1) * 384;
                    dst = ST2 + (i & 1) * 1280;
                }
                short8 sfrag = *(const short8*)(st + frag_off);
                f32x4 ax0v = axb[tts[0] * 64 + q * 16 + c];
                f32x4 ax1v = axb[tts[1] * 64 + q * 16 + c];
                f32x4 ax2v = axb[tts[2] * 64 + q * 16 + c];

                f32x4 p0 = side2p(whhh[0], whhl[0], sfrag, ax0v);
                f32x4 p1 = side2p(whhh[1], whhl[1], sfrag, ax1v);
                f32x4 p2 = side2p(whhh[2], whhl[2], sfrag, bhv2);

                float hv[4];
#pragma unroll
                for (int r = 0; r < 4; ++r) {
                    float rg = sigm(p0[r]);
                    float zg = sigm(p1[r]);
                    float ng = tanh_(ax2v[r] + rg * p2[r]);
                    float hN = ng + zg * (hst[r] - ng);
                    hst[r] = hN;
                    hv[r] = hN;
                }
                unsigned w0 = cvtpk(hv[0], hv[1]);
                unsigned w1 = cvtpk(hv[2], hv[3]);
                uint2v wpk = {w0, w1};
                *(uint2v*)(dst + wr_off) = wpk;
                __builtin_amdgcn_s_setprio(0);
            }
        } else if (L == 0) {
            // ---- T14 x staging: issue loads at phase 0, ds_write at phase 8 ----
            if ((i & 15) == 0) {
                const int base = i + 16;
                if (base < SEQ) {
                    const int hidx = tid - 256;          // 0..127
                    const int row = hidx & 15, so = hidx >> 4;
                    xr0 = *(const f32x4*)(x + ((long)(b0 + row) * SEQ + base + so) * 4);
                    xr1 = *(const f32x4*)(x + ((long)(b0 + row) * SEQ + base + so + 8) * 4);
                }
            } else if ((i & 15) == 8) {
                const int base = i + 8;                  // == issue-time base
                if (base < SEQ) {
                    const int hidx = tid - 256;
                    const int row = hidx & 15, so = hidx >> 4;
                    XS[((base + so) & 31) * 16 + row] = xr0;
                    XS[((base + so + 8) & 31) * 16 + row] = xr1;
                }
            }
            // ---- AX0 for step i+1 (exact fp32 x-matvec) ----
            const int step = i + 1;
            if (step < SEQ) {
                f32x4 xv = XS[(step & 31) * 16 + c];
                f32x4* dstax = AX0 + (step & 1) * 384;
#pragma unroll
                for (int j = 0; j < 3; ++j) {
                    f32x4 a;
#pragma unroll
                    for (int r = 0; r < 4; ++r) {
                        f32x4 w = wx0[4 * j + r];
                        a[r] = bxs[4 * j + r] + w[0] * xv[0] + w[1] * xv[1]
                             + w[2] * xv[2] + w[3] * xv[3];
                    }
                    dstax[tts[j] * 64 + q * 16 + c] = a;
                }
            }
        } else {
            // ---- L1 helper: P[i] = Wih1 * h1[i-1] + biases -> AX1[i&1] ----
            if (i >= 1 && i <= SEQ) {
                const char* us = ST01 + ((i + 1) & 1) * 1280;   // h1[i-1]
                short8 uf = *(const short8*)(us + frag_off);
                f32x4* dstax = AX1 + (i & 1) * 384;
#pragma unroll
                for (int j = 0; j < 3; ++j) {
                    f32x4 a = side2(wuh[j], wul[j], uf, bxv[j]);
                    dstax[tts[j] * 64 + q * 16 + c] = a;
                }
            }
        }
        BSYNC();
    }

    // ---------------- epilogue: out = Weff . h2 + cst ----------------
    if (role == 0 && L == 1) {
        float we[4] = {0, 0, 0, 0};
        const float* w2p = Wfc2 + 16 * hf + 4 * q;
#pragma unroll 8
        for (int j = 0; j < 32; ++j) {
            float wf = Wfc[j];
            f32x4 w2 = *(const f32x4*)(w2p + j * 32);
#pragma unroll
            for (int r = 0; r < 4; ++r) we[r] += wf * w2[r];
        }
        float acc = we[0] * hst[0] + we[1] * hst[1] + we[2] * hst[2] + we[3] * hst[3];
        acc += __shfl_xor(acc, 16);
        acc += __shfl_xor(acc, 32);
        if (q == 0) EP[hf * 16 + c] = acc;
    }
    __syncthreads();
    if (wid == 0 && q == 0) {
        float cst = bfc[0];
        for (int j = 0; j < 32; ++j) cst += Wfc[j] * bfc2[j];
        out[b0 + c] = EP[c] + EP[16 + c] + cst;
    }
}

extern "C" void kernel_launch(void* const* d_in, const int* in_sizes, int n_in,
                              void* d_out, int out_size, void* d_ws, size_t ws_size,
                              hipStream_t stream) {
    const float* x    = (const float*)d_in[0];
    const float* Wih0 = (const float*)d_in[1];
    const float* Whh0 = (const float*)d_in[2];
    const float* bih0 = (const float*)d_in[3];
    const float* bhh0 = (const float*)d_in[4];
    const float* Wih1 = (const float*)d_in[5];
    const float* Whh1 = (const float*)d_in[6];
    const float* bih1 = (const float*)d_in[7];
    const float* bhh1 = (const float*)d_in[8];
    const float* Wfc2 = (const float*)d_in[9];
    const float* bfc2 = (const float*)d_in[10];
    const float* Wfc  = (const float*)d_in[11];
    const float* bfc  = (const float*)d_in[12];

    const int nblocks = out_size / 16;  // 4096/16 = 256 -> 1 block/CU
    hipLaunchKernelGGL(gru_fused, dim3(nblocks), dim3(512), 0, stream,
                       x, Wih0, Whh0, bih0, bhh0, Wih1, Whh1, bih1, bhh1,
                       Wfc2, bfc2, Wfc, bfc, (float*)d_out);
}

// Round 13
// 211.538 us; speedup vs baseline: 2.0163x; 1.0927x over previous
//
#include <hip/hip_runtime.h>

// 2-layer GRU (B=4096, S=512, IN=4, H=32) + FC(32->32) + FC(32->1), fp32 in/out.
// R10 structure (best, 211us): 8 waves/block = (role: main/helper) x (layer) x
// (unit-half hf); main+helper paired per SIMD; lgkm-only barrier; T14 split
// x-staging. 256 blocks x 16 batch rows.
// R13 single change vs R10: mains' gate computation restructured into explicit
// latency phases (batch all independent exps, then rcps; z-rcp fills n-exp
// latency) so the 4 r-chains pipeline instead of executing serially. Same FP
// ops on same inputs, reordered only -> absmax must stay 0.0004882812.
// Lags (verified R7): M0 step i @ iter i; H1 makes AX1[step i-1] @ iter i;
// M1 step i-2 @ iter i; 514 iterations.

#define SEQ 512
#define LOG2E 1.44269504088896340736f

// lgkm-only barrier: orders LDS producer->consumer without draining vmcnt
#define BSYNC() asm volatile("s_waitcnt lgkmcnt(0)\ns_barrier" ::: "memory")

typedef __attribute__((ext_vector_type(8))) short  short8;
typedef __attribute__((ext_vector_type(4))) float  f32x4;
typedef __attribute__((ext_vector_type(2))) unsigned uint2v;

static __device__ __forceinline__ unsigned short f2bf(float f) {
    unsigned u = __builtin_bit_cast(unsigned, f);
    return (unsigned short)((u + 0x7fffu + ((u >> 16) & 1u)) >> 16);
}
static __device__ __forceinline__ float bf2f(unsigned short b) {
    return __builtin_bit_cast(float, ((unsigned)b) << 16);
}
static __device__ __forceinline__ unsigned cvtpk(float a, float b) {
    unsigned r;
    asm("v_cvt_pk_bf16_f32 %0, %1, %2" : "=v"(r) : "v"(a), "v"(b));
    return r;
}
static __device__ __forceinline__ float sigm(float x) {
    return __builtin_amdgcn_rcpf(1.0f + __builtin_amdgcn_exp2f(-LOG2E * x));
}
static __device__ __forceinline__ float tanh_(float x) {
    return 1.0f - 2.0f * __builtin_amdgcn_rcpf(1.0f + __builtin_amdgcn_exp2f((2.0f * LOG2E) * x));
}

#define MFMA(A, B, C) __builtin_amdgcn_mfma_f32_16x16x32_bf16((A), (B), (C), 0, 0, 0)

// (Whi + Wlo) * B + Cin, chained accumulate (2 MFMAs, depth 2)
static __device__ __forceinline__ f32x4 side2(short8 Wh, short8 Wl, short8 B,
                                              f32x4 Cin) {
    f32x4 a = MFMA(Wh, B, Cin);
    a = MFMA(Wl, B, a);
    return a;
}

static __device__ __forceinline__ void cvt8(const float* p, short8& h8, short8& l8) {
    f32x4 v0 = *(const f32x4*)p;
    f32x4 v1 = *(const f32x4*)(p + 4);
#pragma unroll
    for (int e = 0; e < 8; ++e) {
        float v = (e < 4) ? v0[e] : v1[e - 4];
        unsigned short hb = f2bf(v);
        h8[e] = (short)hb;
        l8[e] = (short)f2bf(v - bf2f(hb));
    }
}

__global__ __launch_bounds__(512, 1) void gru_fused(
    const float* __restrict__ x,
    const float* __restrict__ Wih0, const float* __restrict__ Whh0,
    const float* __restrict__ bih0, const float* __restrict__ bhh0,
    const float* __restrict__ Wih1, const float* __restrict__ Whh1,
    const float* __restrict__ bih1, const float* __restrict__ bhh1,
    const float* __restrict__ Wfc2, const float* __restrict__ bfc2,
    const float* __restrict__ Wfc,  const float* __restrict__ bfc,
    float* __restrict__ out)
{
    const int tid  = threadIdx.x;
    const int lane = tid & 63;
    const int wid  = tid >> 6;          // 0..7  (SIMD = wid & 3)
    const int role = wid >> 2;          // 0 = main, 1 = helper
    const int L    = (wid >> 1) & 1;    // layer
    const int hf   = wid & 1;           // unit half
    const int c    = lane & 15;         // batch col
    const int q    = lane >> 4;         // 0..3
    const int b0   = blockIdx.x * 16;

    // LDS map:
    //  ST01: h1 frags (L0 state AND L1-helper input), 2 bufs x [16][80B] = 2560
    //  ST2 : h2 frags, 2 bufs x [16][80B]                                = 2560
    //  XS  : x ring, 32 steps x 16 rows x 16B                            = 8192
    //  AX0 : L0 preact, 2 bufs x 6 tiles x 4 q x 16 c x f32x4            = 12288
    //  AX1 : L1 preact, same                                             = 12288
    //  EP  : epilogue scratch                                            = 128
    __shared__ __align__(16) char smem[38016];
    char*  ST01 = smem;
    char*  ST2  = smem + 2560;
    f32x4* XS   = (f32x4*)(smem + 5120);
    f32x4* AX0  = (f32x4*)(smem + 13312);
    f32x4* AX1  = (f32x4*)(smem + 25600);
    float* EP   = (float*)(smem + 37888);

    // zero state buffers (h = 0)
    for (int i = tid; i < 1280; i += 512) ((unsigned*)smem)[i] = 0u;

    // stage x steps 0..31
    if (tid < 256) {
        const int row = tid & 15, so = tid >> 4;
#pragma unroll
        for (int k = 0; k < 2; ++k) {
            const int step = so + 16 * k;
            XS[step * 16 + row] =
                *(const f32x4*)(x + ((long)(b0 + row) * SEQ + step) * 4);
        }
    }

    const int tts[3] = {hf, 2 + hf, 4 + hf};   // r,z,n tiles for this half

    // ------------- per-role weight setup (wave-uniform branches) -----------
    short8 whhh[3], whhl[3];            // mains: Whh hi/lo
    f32x4  bhv2 = {0, 0, 0, 0};        // mains: bhh n-slice (C-in for j=2)
    f32x4  wx0[12];                     // L0 helper: Wih0 rows fp32
    float  bxs[12];                     // L0 helper: folded biases
    short8 wuh[3], wul[3];              // L1 helper: Wih1 hi/lo
    f32x4  bxv[3];                      // L1 helper: folded biases

    if (role == 0) {
        const float* Whp = L ? Whh1 : Whh0;
        const float* bhp = L ? bhh1 : bhh0;
#pragma unroll
        for (int j = 0; j < 3; ++j)
            cvt8(Whp + (16 * tts[j] + c) * 32 + 8 * q, whhh[j], whhl[j]);
        bhv2 = *(const f32x4*)(bhp + 16 * tts[2] + 4 * q);
    } else if (L == 0) {
#pragma unroll
        for (int j = 0; j < 3; ++j)
#pragma unroll
            for (int r = 0; r < 4; ++r) {
                const int g = 16 * tts[j] + 4 * q + r;
                wx0[4 * j + r] = *(const f32x4*)(Wih0 + g * 4);
                bxs[4 * j + r] = bih0[g] + ((j < 2) ? bhh0[g] : 0.0f);
            }
    } else {
#pragma unroll
        for (int j = 0; j < 3; ++j) {
            cvt8(Wih1 + (16 * tts[j] + c) * 32 + 8 * q, wuh[j], wul[j]);
            f32x4 bb = *(const f32x4*)(bih1 + 16 * tts[j] + 4 * q);
            if (j < 2) bb += *(const f32x4*)(bhh1 + 16 * tts[j] + 4 * q);
            bxv[j] = bb;
        }
    }

    // prologue: L0 helper fills AX0 buf0 with step 0 (direct global x read)
    if (role == 1 && L == 0) {
        f32x4 xv = *(const f32x4*)(x + (long)(b0 + c) * (SEQ * 4));
#pragma unroll
        for (int j = 0; j < 3; ++j) {
            f32x4 a;
#pragma unroll
            for (int r = 0; r < 4; ++r) {
                f32x4 w = wx0[4 * j + r];
                a[r] = bxs[4 * j + r] + w[0] * xv[0] + w[1] * xv[1]
                     + w[2] * xv[2] + w[3] * xv[3];
            }
            AX0[tts[j] * 64 + q * 16 + c] = a;
        }
    }

    float hst[4] = {0, 0, 0, 0};   // mains: units 16hf+4q+r, batch c
    f32x4 xr0 = {0, 0, 0, 0}, xr1 = {0, 0, 0, 0};   // T14 staging regs (helpers)
    const int frag_off = c * 80 + q * 16;                 // b128 B-frag read
    const int wr_off   = c * 80 + (16 * hf + 4 * q) * 2;  // b64 D write (hi)

    __syncthreads();

    // ---------------- pipelined main loop: 514 iterations ----------------
#pragma unroll 2
    for (int i = 0; i <= SEQ + 1; ++i) {
        if (role == 0) {
            const bool act = (L == 0) ? (i < SEQ) : (i >= 2);
            if (act) {
                const char*  st;
                const f32x4* axb;
                char*        dst;
                if (L == 0) {
                    st  = ST01 + ((i + 1) & 1) * 1280;
                    axb = AX0 + (i & 1) * 384;
                    dst = ST01 + (i & 1) * 1280;
                } else {
                    st  = ST2 + ((i + 1) & 1) * 1280;
                    axb = AX1 + ((i + 1) & 1) * 384;
                    dst = ST2 + (i & 1) * 1280;
                }
                short8 sfrag = *(const short8*)(st + frag_off);
                f32x4 ax0v = axb[tts[0] * 64 + q * 16 + c];
                f32x4 ax1v = axb[tts[1] * 64 + q * 16 + c];
                f32x4 ax2v = axb[tts[2] * 64 + q * 16 + c];

                f32x4 p0 = side2(whhh[0], whhl[0], sfrag, ax0v);
                f32x4 p1 = side2(whhh[1], whhl[1], sfrag, ax1v);
                f32x4 p2 = side2(whhh[2], whhl[2], sfrag, bhv2);

                // ---- gate phase, explicitly latency-pipelined ----
                // A: all independent exps (r- and z-gate), B: r-rcps,
                // C: n-exps, D: z-rcps (fill C latency), E: n-rcps, F: combine.
                float er[4], ez[4], rg[4], en[4], zg[4], nr[4], hv[4];
#pragma unroll
                for (int r = 0; r < 4; ++r)
                    er[r] = __builtin_amdgcn_exp2f(-LOG2E * p0[r]);
#pragma unroll
                for (int r = 0; r < 4; ++r)
                    ez[r] = __builtin_amdgcn_exp2f(-LOG2E * p1[r]);
#pragma unroll
                for (int r = 0; r < 4; ++r)
                    rg[r] = __builtin_amdgcn_rcpf(1.0f + er[r]);
#pragma unroll
                for (int r = 0; r < 4; ++r)
                    en[r] = __builtin_amdgcn_exp2f((2.0f * LOG2E) *
                                                   (ax2v[r] + rg[r] * p2[r]));
#pragma unroll
                for (int r = 0; r < 4; ++r)
                    zg[r] = __builtin_amdgcn_rcpf(1.0f + ez[r]);
#pragma unroll
                for (int r = 0; r < 4; ++r)
                    nr[r] = __builtin_amdgcn_rcpf(1.0f + en[r]);
#pragma unroll
                for (int r = 0; r < 4; ++r) {
                    float ng = 1.0f - 2.0f * nr[r];
                    float hN = ng + zg[r] * (hst[r] - ng);
                    hst[r] = hN;
                    hv[r] = hN;
                }
                unsigned w0 = cvtpk(hv[0], hv[1]);
                unsigned w1 = cvtpk(hv[2], hv[3]);
                uint2v wpk = {w0, w1};
                *(uint2v*)(dst + wr_off) = wpk;
            }
        } else if (L == 0) {
            // ---- T14 x staging: issue loads at phase 0, ds_write at phase 8 ----
            if ((i & 15) == 0) {
                const int base = i + 16;
                if (base < SEQ) {
                    const int hidx = tid - 256;          // 0..127
                    const int row = hidx & 15, so = hidx >> 4;
                    xr0 = *(const f32x4*)(x + ((long)(b0 + row) * SEQ + base + so) * 4);
                    xr1 = *(const f32x4*)(x + ((long)(b0 + row) * SEQ + base + so + 8) * 4);
                }
            } else if ((i & 15) == 8) {
                const int base = i + 8;                  // == issue-time base
                if (base < SEQ) {
                    const int hidx = tid - 256;
                    const int row = hidx & 15, so = hidx >> 4;
                    XS[((base + so) & 31) * 16 + row] = xr0;
                    XS[((base + so + 8) & 31) * 16 + row] = xr1;
                }
            }
            // ---- AX0 for step i+1 (exact fp32 x-matvec) ----
            const int step = i + 1;
            if (step < SEQ) {
                f32x4 xv = XS[(step & 31) * 16 + c];
                f32x4* dstax = AX0 + (step & 1) * 384;
#pragma unroll
                for (int j = 0; j < 3; ++j) {
                    f32x4 a;
#pragma unroll
                    for (int r = 0; r < 4; ++r) {
                        f32x4 w = wx0[4 * j + r];
                        a[r] = bxs[4 * j + r] + w[0] * xv[0] + w[1] * xv[1]
                             + w[2] * xv[2] + w[3] * xv[3];
                    }
                    dstax[tts[j] * 64 + q * 16 + c] = a;
                }
            }
        } else {
            // ---- L1 helper: P[i] = Wih1 * h1[i-1] + biases -> AX1[i&1] ----
            if (i >= 1 && i <= SEQ) {
                const char* us = ST01 + ((i + 1) & 1) * 1280;   // h1[i-1]
                short8 uf = *(const short8*)(us + frag_off);
                f32x4* dstax = AX1 + (i & 1) * 384;
#pragma unroll
                for (int j = 0; j < 3; ++j) {
                    f32x4 a = side2(wuh[j], wul[j], uf, bxv[j]);
                    dstax[tts[j] * 64 + q * 16 + c] = a;
                }
            }
        }
        BSYNC();
    }

    // ---------------- epilogue: out = Weff . h2 + cst ----------------
    if (role == 0 && L == 1) {
        float we[4] = {0, 0, 0, 0};
        const float* w2p = Wfc2 + 16 * hf + 4 * q;
#pragma unroll 8
        for (int j = 0; j < 32; ++j) {
            float wf = Wfc[j];
            f32x4 w2 = *(const f32x4*)(w2p + j * 32);
#pragma unroll
            for (int r = 0; r < 4; ++r) we[r] += wf * w2[r];
        }
        float acc = we[0] * hst[0] + we[1] * hst[1] + we[2] * hst[2] + we[3] * hst[3];
        acc += __shfl_xor(acc, 16);
        acc += __shfl_xor(acc, 32);
        if (q == 0) EP[hf * 16 + c] = acc;
    }
    __syncthreads();
    if (wid == 0 && q == 0) {
        float cst = bfc[0];
        for (int j = 0; j < 32; ++j) cst += Wfc[j] * bfc2[j];
        out[b0 + c] = EP[c] + EP[16 + c] + cst;
    }
}

extern "C" void kernel_launch(void* const* d_in, const int* in_sizes, int n_in,
                              void* d_out, int out_size, void* d_ws, size_t ws_size,
                              hipStream_t stream) {
    const float* x    = (const float*)d_in[0];
    const float* Wih0 = (const float*)d_in[1];
    const float* Whh0 = (const float*)d_in[2];
    const float* bih0 = (const float*)d_in[3];
    const float* bhh0 = (const float*)d_in[4];
    const float* Wih1 = (const float*)d_in[5];
    const float* Whh1 = (const float*)d_in[6];
    const float* bih1 = (const float*)d_in[7];
    const float* bhh1 = (const float*)d_in[8];
    const float* Wfc2 = (const float*)d_in[9];
    const float* bfc2 = (const float*)d_in[10];
    const float* Wfc  = (const float*)d_in[11];
    const float* bfc  = (const float*)d_in[12];

    const int nblocks = out_size / 16;  // 4096/16 = 256 -> 1 block/CU
    hipLaunchKernelGGL(gru_fused, dim3(nblocks), dim3(512), 0, stream,
                       x, Wih0, Whh0, bih0, bhh0, Wih1, Whh1, bih1, bhh1,
                       Wfc2, bfc2, Wfc, bfc, (float*)d_out);
}